// Round 1
// baseline (460.025 us; speedup 1.0000x reference)
//
#include <hip/hip_runtime.h>

// ---------------------------------------------------------------------------
// NHRepNet fused forward: 8-layer MLP + CSG combine, bf16 MFMA path.
//
// Math per point (fp32 reference):
//   h = x (3)
//   L0: 3->256, softplus(100z)/100
//   L1,L2: 256->256, softplus
//   L3: 256->253, softplus, then h = concat(h, x) * 1/sqrt(2)  (-> 256)
//   L4..L6: 256->256, softplus
//   L7: 256->8 (bias -1ish), no activation -> branch vals v0..v7
//   hcsg = max(v0, v1, min(v2,v3), min(v4, v5, max(v6,v7)))
//   out[pt] = [hcsg, v0..v7]   (9 fp32)
//
// Strategy: per block = 64 points, 4 waves. Activations in LDS [64][264] bf16
// (pad 264 -> row stride 528B = 132 dwords, bank offset 4/row => free 2-way).
// Compute OUT^T = W^T * ACT^T with v_mfma_f32_16x16x32_bf16:
//   A-operand = W^T fragments, pre-packed to bf16 in d_ws in exact frag order
//               (coalesced global_load_dwordx4, wave owns 64-ch strip => W read
//               exactly once per block per layer)
//   B-operand = activations, contiguous 16B ds_read_b128
//   C layout (verified m89/m91): col=lane&15 (point), row=quad*4+reg (channel)
//               => 4 consecutive channels per lane => ds_write_b64 per (mt,nt)
// ---------------------------------------------------------------------------

using bf16x8 = __attribute__((ext_vector_type(8))) __bf16;
using f32x4  = __attribute__((ext_vector_type(4))) float;

#define LDA 264   // padded activation row length (bf16 elems)

// ws layout (offsets in elements):
//   W frags (bf16/ushort): per layer MT*KK*64*8 elems
#define OFFW0 0        // L0: MT=16 KK=1  -> 8192
#define OFFW1 8192     // L1: MT=16 KK=8  -> 65536
#define OFFW2 73728
#define OFFW3 139264
#define OFFW4 204800
#define OFFW5 270336
#define OFFW6 335872
#define OFFW7 401408   // L7: MT=1 KK=8 -> 4096; total 405504 elems = 811008 B
#define WSB_BYTE_OFF 811008
//   biases (fp32, padded to MT*16): L0..L6 at l*256, L7 at 1792 (16 floats)
#define OFFB0 0
#define OFFB1 256
#define OFFB2 512
#define OFFB3 768
#define OFFB4 1024
#define OFFB5 1280
#define OFFB6 1536
#define OFFB7 1792

__device__ __forceinline__ unsigned short bf16_rne(float f) {
    unsigned int u = __float_as_uint(f);
    unsigned int r = u + 0x7FFFu + ((u >> 16) & 1u);
    return (unsigned short)(r >> 16);
}

__device__ __forceinline__ float softplus100(float v) {
    // softplus(100v)/100, numerically stable; matches jax.nn.softplus to fp32 noise
    float t = 100.0f * v;
    float e = __expf(-fabsf(t));
    return (fmaxf(t, 0.0f) + __logf(1.0f + e)) * 0.01f;
}

// Generic 256-out layer. Wave w computes channels [w*64, w*64+64) for all 64 pts.
// MODE 0: softplus.  MODE 1: layer-3 (softplus, *1/sqrt2, splice x into ch 253..255).
template <int KK, int MODE>
__device__ __forceinline__ void layer_mm(
    const unsigned short* __restrict__ wfrag,   // this layer's packed A-frags
    const float* __restrict__ bias,             // padded bias (256 floats)
    const unsigned short* src, unsigned short* dst,  // LDS act buffers [64][LDA]
    const float* xst,                           // LDS x stash [64][4] fp32
    int wave, int lane)
{
    const int quad = lane >> 4;
    const int l15  = lane & 15;

    f32x4 acc[4][4];   // [mt_local][nt]
#pragma unroll
    for (int i = 0; i < 4; ++i)
#pragma unroll
        for (int nt = 0; nt < 4; ++nt)
            acc[i][nt] = f32x4{0.0f, 0.0f, 0.0f, 0.0f};

    for (int kk = 0; kk < KK; ++kk) {
        bf16x8 bfr[4];
#pragma unroll
        for (int nt = 0; nt < 4; ++nt)
            bfr[nt] = *(const bf16x8*)(src + (nt * 16 + l15) * LDA + kk * 32 + quad * 8);
#pragma unroll
        for (int i = 0; i < 4; ++i) {
            const int mt = wave * 4 + i;
            bf16x8 afr = *(const bf16x8*)(wfrag + ((mt * KK + kk) * 64 + lane) * 8);
#pragma unroll
            for (int nt = 0; nt < 4; ++nt)
                acc[i][nt] = __builtin_amdgcn_mfma_f32_16x16x32_bf16(afr, bfr[nt], acc[i][nt], 0, 0, 0);
        }
    }

    // epilogue: bias + activation + bf16 pack + LDS write (4 consecutive channels)
#pragma unroll
    for (int i = 0; i < 4; ++i) {
        const int chb = (wave * 4 + i) * 16 + quad * 4;
        const float b0 = bias[chb + 0], b1 = bias[chb + 1];
        const float b2 = bias[chb + 2], b3 = bias[chb + 3];
#pragma unroll
        for (int nt = 0; nt < 4; ++nt) {
            const int pt = nt * 16 + l15;
            float vr[4];
            vr[0] = acc[i][nt][0] + b0;
            vr[1] = acc[i][nt][1] + b1;
            vr[2] = acc[i][nt][2] + b2;
            vr[3] = acc[i][nt][3] + b3;
            unsigned short ov[4];
#pragma unroll
            for (int r = 0; r < 4; ++r) {
                float vv = softplus100(vr[r]);
                if (MODE == 1) {
                    vv *= 0.70710678118654752f;
                    const int ch = chb + r;
                    if (ch >= 253)  // splice x * 1/sqrt2 (skip-concat)
                        vv = xst[pt * 4 + (ch - 253)] * 0.70710678118654752f;
                }
                ov[r] = bf16_rne(vv);
            }
            ushort4 pack;
            pack.x = ov[0]; pack.y = ov[1]; pack.z = ov[2]; pack.w = ov[3];
            *(ushort4*)(dst + pt * LDA + chb) = pack;   // 8B LDS write, aligned
        }
    }
}

__global__ __launch_bounds__(256, 2)
void nhrep_main(const float* __restrict__ x, float* __restrict__ out,
                const unsigned short* __restrict__ wsW,
                const float* __restrict__ wsB, int npts)
{
    __shared__ unsigned short actA[64 * LDA];
    __shared__ unsigned short actB[64 * LDA];
    __shared__ float xst[64 * 4];
    __shared__ float bv[64 * 8];

    const int tid  = threadIdx.x;
    const int wave = tid >> 6, lane = tid & 63;
    const int quad = lane >> 4, l15 = lane & 15;
    const int base_pt = blockIdx.x * 64;

    // stage x into actA channels 0..2, zero-pad to 32 (K-pad for layer 0)
    for (int i = tid; i < 64 * 32; i += 256) {
        const int pt = i >> 5, ch = i & 31;
        const int ptg = base_pt + pt;
        float v = 0.0f;
        if (ch < 3 && ptg < npts) v = x[ptg * 3 + ch];
        actA[pt * LDA + ch] = bf16_rne(v);
        if (ch < 4) xst[pt * 4 + ch] = (ch < 3) ? v : 0.0f;
    }
    __syncthreads();

    layer_mm<1, 0>(wsW + OFFW0, wsB + OFFB0, actA, actB, xst, wave, lane);
    __syncthreads();
    layer_mm<8, 0>(wsW + OFFW1, wsB + OFFB1, actB, actA, xst, wave, lane);
    __syncthreads();
    layer_mm<8, 0>(wsW + OFFW2, wsB + OFFB2, actA, actB, xst, wave, lane);
    __syncthreads();
    layer_mm<8, 1>(wsW + OFFW3, wsB + OFFB3, actB, actA, xst, wave, lane);
    __syncthreads();
    layer_mm<8, 0>(wsW + OFFW4, wsB + OFFB4, actA, actB, xst, wave, lane);
    __syncthreads();
    layer_mm<8, 0>(wsW + OFFW5, wsB + OFFB5, actB, actA, xst, wave, lane);
    __syncthreads();
    layer_mm<8, 0>(wsW + OFFW6, wsB + OFFB6, actA, actB, xst, wave, lane);
    __syncthreads();

    // layer 7: 256 -> 8 (one zero-padded M-tile). wave w handles its own 16 pts.
    {
        f32x4 acc = f32x4{0.0f, 0.0f, 0.0f, 0.0f};
        const unsigned short* w7 = wsW + OFFW7;
#pragma unroll
        for (int kk = 0; kk < 8; ++kk) {
            bf16x8 bfr = *(const bf16x8*)(actB + (wave * 16 + l15) * LDA + kk * 32 + quad * 8);
            bf16x8 afr = *(const bf16x8*)(w7 + (kk * 64 + lane) * 8);
            acc = __builtin_amdgcn_mfma_f32_16x16x32_bf16(afr, bfr, acc, 0, 0, 0);
        }
        if (quad < 2) {   // real channels 0..7 live in quads 0,1
            const float* b7 = wsB + OFFB7;
            float4 o;
            o.x = acc[0] + b7[quad * 4 + 0];
            o.y = acc[1] + b7[quad * 4 + 1];
            o.z = acc[2] + b7[quad * 4 + 2];
            o.w = acc[3] + b7[quad * 4 + 3];
            *(float4*)(bv + (wave * 16 + l15) * 8 + quad * 4) = o;
        }
    }
    __syncthreads();

    // CSG combine + output (lane quad 0 of each wave handles its 16 points)
    if (quad == 0) {
        const int pt  = wave * 16 + l15;
        const int ptg = base_pt + pt;
        if (ptg < npts) {
            const float v0 = bv[pt * 8 + 0], v1 = bv[pt * 8 + 1];
            const float v2 = bv[pt * 8 + 2], v3 = bv[pt * 8 + 3];
            const float v4 = bv[pt * 8 + 4], v5 = bv[pt * 8 + 5];
            const float v6 = bv[pt * 8 + 6], v7 = bv[pt * 8 + 7];
            const float m23   = fminf(v2, v3);
            const float m67   = fmaxf(v6, v7);
            const float m4567 = fminf(fminf(v4, v5), m67);
            const float h     = fmaxf(fmaxf(v0, v1), fmaxf(m23, m4567));
            float* o = out + (long)ptg * 9;
            o[0] = h;
            o[1] = v0; o[2] = v1; o[3] = v2; o[4] = v3;
            o[5] = v4; o[6] = v5; o[7] = v6; o[8] = v7;
        }
    }
}

// ---------------------------------------------------------------------------
// Prepack: W (fp32 [in_d][out_d] row-major) -> bf16 A-operand fragments for
// OUT^T = W^T * ACT^T.  Frag element (mt,kk,lane,j) = W^T[mt*16 + (lane&15)]
// [kk*32 + (lane>>4)*8 + j], zero-padded outside [in_d, out_d].
// dst index = ((mt*KK + kk)*64 + lane)*8.  Thread t packs one 16B frag.
// ---------------------------------------------------------------------------
__global__ void prepack_w(const float* __restrict__ W, unsigned short* __restrict__ dst,
                          int in_d, int out_d, int KK, int total)
{
    const int t = blockIdx.x * blockDim.x + threadIdx.x;
    if (t >= total) return;
    const int lane = t & 63;
    const int kk   = (t >> 6) % KK;
    const int mt   = t / (64 * KK);
    const int o    = mt * 16 + (lane & 15);
    const int kb   = kk * 32 + (lane >> 4) * 8;

    unsigned short v[8];
#pragma unroll
    for (int j = 0; j < 8; ++j) {
        const int k = kb + j;
        float w = 0.0f;
        if (k < in_d && o < out_d) w = W[k * out_d + o];
        v[j] = bf16_rne(w);
    }
    uint4 p;
    p.x = (unsigned int)v[0] | ((unsigned int)v[1] << 16);
    p.y = (unsigned int)v[2] | ((unsigned int)v[3] << 16);
    p.z = (unsigned int)v[4] | ((unsigned int)v[5] << 16);
    p.w = (unsigned int)v[6] | ((unsigned int)v[7] << 16);
    *(uint4*)(dst + t * 8) = p;
}

__global__ void prepack_b(const float* __restrict__ b, float* __restrict__ dst,
                          int n_real, int n_pad)
{
    const int t = blockIdx.x * blockDim.x + threadIdx.x;
    if (t < n_pad) dst[t] = (t < n_real) ? b[t] : 0.0f;
}

extern "C" void kernel_launch(void* const* d_in, const int* in_sizes, int n_in,
                              void* d_out, int out_size, void* d_ws, size_t ws_size,
                              hipStream_t stream)
{
    const float* x = (const float*)d_in[0];
    unsigned short* wsW = (unsigned short*)d_ws;
    float* wsB = (float*)((char*)d_ws + WSB_BYTE_OFF);

    static const int KKs[8]  = {1, 8, 8, 8, 8, 8, 8, 8};
    static const int MTs[8]  = {16, 16, 16, 16, 16, 16, 16, 1};
    static const int ind[8]  = {3, 256, 256, 256, 256, 256, 256, 256};
    static const int outd[8] = {256, 256, 256, 253, 256, 256, 256, 8};
    static const int OFFW[8] = {OFFW0, OFFW1, OFFW2, OFFW3, OFFW4, OFFW5, OFFW6, OFFW7};
    static const int OFFB[8] = {OFFB0, OFFB1, OFFB2, OFFB3, OFFB4, OFFB5, OFFB6, OFFB7};

    for (int l = 0; l < 8; ++l) {
        const float* W = (const float*)d_in[1 + 2 * l];
        const float* b = (const float*)d_in[2 + 2 * l];
        const int total = MTs[l] * KKs[l] * 64;
        prepack_w<<<(total + 255) / 256, 256, 0, stream>>>(
            W, wsW + OFFW[l], ind[l], outd[l], KKs[l], total);
        prepack_b<<<1, 256, 0, stream>>>(b, wsB + OFFB[l], outd[l], MTs[l] * 16);
    }

    const int npts = in_sizes[0] / 3;   // 100000
    const int nblk = (npts + 63) / 64;
    nhrep_main<<<nblk, 256, 0, stream>>>(x, (float*)d_out, wsW, wsB, npts);
}

// Round 2
// 230.183 us; speedup vs baseline: 1.9985x; 1.9985x over previous
//
#include <hip/hip_runtime.h>
#include <hip/hip_bf16.h>

// ---------------------------------------------------------------------------
// NHRepNet fused forward: 8-layer MLP + CSG combine, bf16 MFMA path. Round 2.
//
// R2 changes vs R1 (which ran 365us main / 460us total, MfmaUtil 9%, Occ 20%):
//  - single in-place LDS activation buffer (compute->barrier->write->barrier):
//    LDS 70.6KB -> 36.9KB => 4 blocks/CU (16 waves/CU) instead of 2
//  - bias preloaded into MFMA accumulators (no epilogue adds)
//  - softplus in exp2 domain: mul, v_exp(-abs mod), add, v_log, max, fma
//  - packed bf16 convert via __float22bfloat162_rn (v_cvt_pk_bf16_f32)
//  - all 17 prepack launches fused into ONE kernel (saves ~90us launch gaps)
// ---------------------------------------------------------------------------

using bf16x8 = __attribute__((ext_vector_type(8))) __bf16;
using f32x4  = __attribute__((ext_vector_type(4))) float;

#define LDA 264   // padded activation row length (bf16 elems); 528B row = bank+4/row

// W frag element offsets in ws (ushort): layer l starts at FRAG_BASE[l]*8
#define OFFW0 0
#define OFFW1 8192
#define OFFW2 73728
#define OFFW3 139264
#define OFFW4 204800
#define OFFW5 270336
#define OFFW6 335872
#define OFFW7 401408
#define WSB_BYTE_OFF 811008   // start of fp32 bias region
#define OFFB7 1792            // L0..L6 at l*256; L7 at 1792 (16 floats)

__device__ __forceinline__ float fast_exp2(float x) {
#if __has_builtin(__builtin_amdgcn_exp2f)
    return __builtin_amdgcn_exp2f(x);
#else
    return __expf(x * 0.6931471805599453f);
#endif
}
__device__ __forceinline__ float fast_log2(float x) {
#if __has_builtin(__builtin_amdgcn_logf)
    return __builtin_amdgcn_logf(x);
#else
    return __log2f(x);
#endif
}

// softplus(100v)/100 = max(v,0) + ln(1 + e^{-100|v|})/100, exp2-domain (6 VALU)
__device__ __forceinline__ float softplus100(float v) {
    float t = v * 144.26950408889634f;          // 100*log2(e)
    float e = fast_exp2(-fabsf(t));             // -abs folds to input modifier
    float l = fast_log2(1.0f + e);
    return fmaf(l, 0.006931471805599453f, fmaxf(v, 0.0f));   // ln2/100
}

__device__ __forceinline__ unsigned short bf16_rne(float f) {
    unsigned int u = __float_as_uint(f);
    unsigned int r = u + 0x7FFFu + ((u >> 16) & 1u);
    return (unsigned short)(r >> 16);
}

// One 256-out layer, in-place on act[64][LDA]. Wave w owns output channels
// [w*64, w*64+64). MODE 0: softplus. MODE 1: layer-3 (softplus, *1/sqrt2,
// splice x*1/sqrt2 into ch 253..255).
template <int KK, int MODE>
__device__ __forceinline__ void layer_mm(
    const unsigned short* __restrict__ wfrag,
    const float* __restrict__ bias,
    unsigned short* act, const float* xst,
    int wave, int lane)
{
    const int quad = lane >> 4;
    const int l15  = lane & 15;

    // init acc with bias (C row = quad*4+reg -> channel chb+reg, same for all pts)
    f32x4 acc[4][4];
#pragma unroll
    for (int i = 0; i < 4; ++i) {
        const int chb = (wave * 4 + i) * 16 + quad * 4;
        const float4 b4 = *(const float4*)(bias + chb);
#pragma unroll
        for (int nt = 0; nt < 4; ++nt)
            acc[i][nt] = f32x4{b4.x, b4.y, b4.z, b4.w};
    }

#pragma unroll
    for (int kk = 0; kk < KK; ++kk) {
        bf16x8 bfr[4];
#pragma unroll
        for (int nt = 0; nt < 4; ++nt)
            bfr[nt] = *(const bf16x8*)(act + (nt * 16 + l15) * LDA + kk * 32 + quad * 8);
#pragma unroll
        for (int i = 0; i < 4; ++i) {
            const int mt = wave * 4 + i;
            bf16x8 afr = *(const bf16x8*)(wfrag + ((mt * KK + kk) * 64 + lane) * 8);
#pragma unroll
            for (int nt = 0; nt < 4; ++nt)
                acc[i][nt] = __builtin_amdgcn_mfma_f32_16x16x32_bf16(afr, bfr[nt], acc[i][nt], 0, 0, 0);
        }
    }

    __syncthreads();   // all waves done READING act

#pragma unroll
    for (int i = 0; i < 4; ++i) {
        const int chb = (wave * 4 + i) * 16 + quad * 4;
#pragma unroll
        for (int nt = 0; nt < 4; ++nt) {
            const int pt = nt * 16 + l15;
            float vv[4];
#pragma unroll
            for (int r = 0; r < 4; ++r) {
                float s = softplus100(acc[i][nt][r]);
                if (MODE == 1) {
                    s *= 0.70710678118654752f;
                    const int ch = chb + r;
                    if (ch >= 253)  // splice x * 1/sqrt2 (skip-concat)
                        s = xst[pt * 4 + (ch - 253)] * 0.70710678118654752f;
                }
                vv[r] = s;
            }
            __hip_bfloat162 p01 = __float22bfloat162_rn(float2{vv[0], vv[1]});
            __hip_bfloat162 p23 = __float22bfloat162_rn(float2{vv[2], vv[3]});
            uint2 pk;
            pk.x = *(unsigned int*)&p01;
            pk.y = *(unsigned int*)&p23;
            *(uint2*)(act + pt * LDA + chb) = pk;    // 8B aligned LDS write
        }
    }

    __syncthreads();   // writes visible before next layer reads
}

__global__ __launch_bounds__(256, 4)
void nhrep_main(const float* __restrict__ x, float* __restrict__ out,
                const unsigned short* __restrict__ wsW,
                const float* __restrict__ wsB, int npts)
{
    __shared__ unsigned short act[64 * LDA];   // 33792 B
    __shared__ float xst[64 * 4];              // 1024 B
    __shared__ float bv[64 * 8];               // 2048 B

    const int tid  = threadIdx.x;
    const int wave = tid >> 6, lane = tid & 63;
    const int quad = lane >> 4, l15 = lane & 15;
    const int base_pt = blockIdx.x * 64;

    // stage x into act channels 0..2, zero-pad to 32 (K-pad for layer 0)
    for (int i = tid; i < 64 * 32; i += 256) {
        const int pt = i >> 5, ch = i & 31;
        const int ptg = base_pt + pt;
        float v = 0.0f;
        if (ch < 3 && ptg < npts) v = x[ptg * 3 + ch];
        act[pt * LDA + ch] = bf16_rne(v);
        if (ch < 4) xst[pt * 4 + ch] = (ch < 3) ? v : 0.0f;
    }
    __syncthreads();

    layer_mm<1, 0>(wsW + OFFW0, wsB + 0 * 256, act, xst, wave, lane);
    layer_mm<8, 0>(wsW + OFFW1, wsB + 1 * 256, act, xst, wave, lane);
    layer_mm<8, 0>(wsW + OFFW2, wsB + 2 * 256, act, xst, wave, lane);
    layer_mm<8, 1>(wsW + OFFW3, wsB + 3 * 256, act, xst, wave, lane);
    layer_mm<8, 0>(wsW + OFFW4, wsB + 4 * 256, act, xst, wave, lane);
    layer_mm<8, 0>(wsW + OFFW5, wsB + 5 * 256, act, xst, wave, lane);
    layer_mm<8, 0>(wsW + OFFW6, wsB + 6 * 256, act, xst, wave, lane);

    // layer 7: 256 -> 8 (one zero-padded M-tile). wave w handles its own 16 pts.
    {
        const float4 b4 = *(const float4*)(wsB + OFFB7 + quad * 4);  // quads>=2 read pad zeros
        f32x4 acc = f32x4{b4.x, b4.y, b4.z, b4.w};
        const unsigned short* w7 = wsW + OFFW7;
#pragma unroll
        for (int kk = 0; kk < 8; ++kk) {
            bf16x8 bfr = *(const bf16x8*)(act + (wave * 16 + l15) * LDA + kk * 32 + quad * 8);
            bf16x8 afr = *(const bf16x8*)(w7 + (kk * 64 + lane) * 8);
            acc = __builtin_amdgcn_mfma_f32_16x16x32_bf16(afr, bfr, acc, 0, 0, 0);
        }
        if (quad < 2) {   // real channels 0..7 live in quads 0,1
            float4 o;
            o.x = acc[0]; o.y = acc[1]; o.z = acc[2]; o.w = acc[3];
            *(float4*)(bv + (wave * 16 + l15) * 8 + quad * 4) = o;
        }
    }
    __syncthreads();

    // CSG combine + output (lane quad 0 of each wave handles its 16 points)
    if (quad == 0) {
        const int pt  = wave * 16 + l15;
        const int ptg = base_pt + pt;
        if (ptg < npts) {
            const float v0 = bv[pt * 8 + 0], v1 = bv[pt * 8 + 1];
            const float v2 = bv[pt * 8 + 2], v3 = bv[pt * 8 + 3];
            const float v4 = bv[pt * 8 + 4], v5 = bv[pt * 8 + 5];
            const float v6 = bv[pt * 8 + 6], v7 = bv[pt * 8 + 7];
            const float m23   = fminf(v2, v3);
            const float m67   = fmaxf(v6, v7);
            const float m4567 = fminf(fminf(v4, v5), m67);
            const float h     = fmaxf(fmaxf(v0, v1), fmaxf(m23, m4567));
            float* o = out + (long)ptg * 9;
            o[0] = h;
            o[1] = v0; o[2] = v1; o[3] = v2; o[4] = v3;
            o[5] = v4; o[6] = v5; o[7] = v6; o[8] = v7;
        }
    }
}

// ---------------------------------------------------------------------------
// ONE fused prepack kernel: all 8 W's -> bf16 A-operand fragments + all 8
// padded biases. Frag (mt,kk,lane,j) = W^T[mt*16+(lane&15)][kk*32+(lane>>4)*8+j]
// zero-padded; global frag index t writes dstW + t*8 (layout is contiguous).
// ---------------------------------------------------------------------------
struct PackArgs {
    const float* W[8];
    const float* b[8];
};

#define TOTAL_FRAGS 50688
#define TOTAL_BIAS  1808

__global__ void prepack_all(PackArgs args, unsigned short* __restrict__ dstW,
                            float* __restrict__ dstB)
{
    const int t = blockIdx.x * blockDim.x + threadIdx.x;
    // frag bases per layer (in 8-elem frags)
    const int FB[9]  = {0, 1024, 9216, 17408, 25600, 33792, 41984, 50176, 50688};
    const int KKs[8] = {1, 8, 8, 8, 8, 8, 8, 8};
    const int ind[8] = {3, 256, 256, 256, 256, 256, 256, 256};
    const int outd[8]= {256, 256, 256, 253, 256, 256, 256, 8};

    if (t < TOTAL_FRAGS) {
        int l = 0;
        while (t >= FB[l + 1]) ++l;
        const int f    = t - FB[l];
        const int lane = f & 63;
        const int kk   = (f >> 6) % KKs[l];
        const int mt   = f / (64 * KKs[l]);
        const int o    = mt * 16 + (lane & 15);
        const int kb   = kk * 32 + (lane >> 4) * 8;
        const float* W = args.W[l];
        const int in_d = ind[l], out_d = outd[l];

        unsigned short v[8];
#pragma unroll
        for (int j = 0; j < 8; ++j) {
            const int k = kb + j;
            float w = 0.0f;
            if (k < in_d && o < out_d) w = W[k * out_d + o];
            unsigned int u = __float_as_uint(w);
            v[j] = (unsigned short)((u + 0x7FFFu + ((u >> 16) & 1u)) >> 16);
        }
        uint4 p;
        p.x = (unsigned int)v[0] | ((unsigned int)v[1] << 16);
        p.y = (unsigned int)v[2] | ((unsigned int)v[3] << 16);
        p.z = (unsigned int)v[4] | ((unsigned int)v[5] << 16);
        p.w = (unsigned int)v[6] | ((unsigned int)v[7] << 16);
        *(uint4*)(dstW + (long)t * 8) = p;
    } else if (t < TOTAL_FRAGS + TOTAL_BIAS) {
        const int u = t - TOTAL_FRAGS;          // bias pad layout: L0..L6 at l*256, L7 at 1792
        const int l = (u < 1792) ? (u >> 8) : 7;
        const int idx = (l < 7) ? (u & 255) : (u - 1792);
        dstB[u] = (idx < outd[l]) ? args.b[l][idx] : 0.0f;
    }
}

extern "C" void kernel_launch(void* const* d_in, const int* in_sizes, int n_in,
                              void* d_out, int out_size, void* d_ws, size_t ws_size,
                              hipStream_t stream)
{
    const float* x = (const float*)d_in[0];
    unsigned short* wsW = (unsigned short*)d_ws;
    float* wsB = (float*)((char*)d_ws + WSB_BYTE_OFF);

    PackArgs pa;
    for (int l = 0; l < 8; ++l) {
        pa.W[l] = (const float*)d_in[1 + 2 * l];
        pa.b[l] = (const float*)d_in[2 + 2 * l];
    }
    const int ptot = TOTAL_FRAGS + TOTAL_BIAS;
    prepack_all<<<(ptot + 255) / 256, 256, 0, stream>>>(pa, wsW, wsB);

    const int npts = in_sizes[0] / 3;   // 100000
    const int nblk = (npts + 63) / 64;
    nhrep_main<<<nblk, 256, 0, stream>>>(x, (float*)d_out, wsW, wsB, npts);
}

// Round 3
// 210.434 us; speedup vs baseline: 2.1861x; 1.0938x over previous
//
#include <hip/hip_runtime.h>
#include <hip/hip_bf16.h>

// ---------------------------------------------------------------------------
// NHRepNet fused forward: 8-layer MLP + CSG combine, bf16 MFMA path. Round 3.
//
// R3 changes vs R2 (main 153us, MfmaUtil 22%, VALUBusy 38%, Occ 35%):
//  - tile 64 -> 48 pts (acc[4][3], LDS 26.9KB) => 5 blocks/CU = 20 waves/CU
//    cap (was 4 blocks = 16 waves). launch_bounds(256,5) -> 102-reg cap.
//  - mixed grid to kill round-quantization: 1280 x 48-pt tiles (round 1,
//    exactly full at 5 blk/CU) + 1205 x 32-pt tiles (round 2, NT=2 template
//    actually skips the 3rd column's work). Both rounds full-width.
//  - CSG epilogue via __shfl (no bv LDS buffer, no final barrier).
// ---------------------------------------------------------------------------

using bf16x8 = __attribute__((ext_vector_type(8))) __bf16;
using f32x4  = __attribute__((ext_vector_type(4))) float;

#define LDA 264   // padded activation row stride (bf16): +4 dwords/row => 2-way free

#define OFFW0 0
#define OFFW1 8192
#define OFFW2 73728
#define OFFW3 139264
#define OFFW4 204800
#define OFFW5 270336
#define OFFW6 335872
#define OFFW7 401408
#define WSB_BYTE_OFF 811008   // start of fp32 bias region in ws
#define OFFB7 1792            // L0..L6 at l*256; L7 at 1792 (16 floats, padded)

__device__ __forceinline__ float fast_exp2(float x) {
#if __has_builtin(__builtin_amdgcn_exp2f)
    return __builtin_amdgcn_exp2f(x);
#else
    return __expf(x * 0.6931471805599453f);
#endif
}
__device__ __forceinline__ float fast_log2(float x) {
#if __has_builtin(__builtin_amdgcn_logf)
    return __builtin_amdgcn_logf(x);
#else
    return __log2f(x);
#endif
}

// softplus(100v)/100 = max(v,0) + ln(1+e^{-100|v|})/100, exp2-domain
__device__ __forceinline__ float softplus100(float v) {
    float t = v * 144.26950408889634f;          // 100*log2(e)
    float e = fast_exp2(-fabsf(t));
    float l = fast_log2(1.0f + e);
    return fmaf(l, 0.006931471805599453f, fmaxf(v, 0.0f));   // ln2/100
}

__device__ __forceinline__ unsigned short bf16_rne(float f) {
    unsigned int u = __float_as_uint(f);
    unsigned int r = u + 0x7FFFu + ((u >> 16) & 1u);
    return (unsigned short)(r >> 16);
}

// One 256-out layer, in-place on act[NT*16][LDA]. Wave w owns channels
// [w*64, w*64+64). MODE 0: softplus. MODE 1: layer-3 (softplus, *1/sqrt2,
// splice x*1/sqrt2 into ch 253..255).
template <int KK, int MODE, int NT>
__device__ __forceinline__ void layer_mm(
    const unsigned short* __restrict__ wfrag,
    const float* __restrict__ bias,
    unsigned short* act, const float* xst,
    int wave, int lane)
{
    const int quad = lane >> 4;
    const int l15  = lane & 15;

    f32x4 acc[4][NT];
#pragma unroll
    for (int i = 0; i < 4; ++i) {
        const int chb = (wave * 4 + i) * 16 + quad * 4;
        const float4 b4 = *(const float4*)(bias + chb);
#pragma unroll
        for (int nt = 0; nt < NT; ++nt)
            acc[i][nt] = f32x4{b4.x, b4.y, b4.z, b4.w};
    }

#pragma unroll
    for (int kk = 0; kk < KK; ++kk) {
        bf16x8 bfr[NT];
#pragma unroll
        for (int nt = 0; nt < NT; ++nt)
            bfr[nt] = *(const bf16x8*)(act + (nt * 16 + l15) * LDA + kk * 32 + quad * 8);
#pragma unroll
        for (int i = 0; i < 4; ++i) {
            const int mt = wave * 4 + i;
            bf16x8 afr = *(const bf16x8*)(wfrag + ((mt * KK + kk) * 64 + lane) * 8);
#pragma unroll
            for (int nt = 0; nt < NT; ++nt)
                acc[i][nt] = __builtin_amdgcn_mfma_f32_16x16x32_bf16(afr, bfr[nt], acc[i][nt], 0, 0, 0);
        }
    }

    __syncthreads();   // all waves done READING act

#pragma unroll
    for (int i = 0; i < 4; ++i) {
        const int chb = (wave * 4 + i) * 16 + quad * 4;
#pragma unroll
        for (int nt = 0; nt < NT; ++nt) {
            const int pt = nt * 16 + l15;
            float vv[4];
#pragma unroll
            for (int r = 0; r < 4; ++r) {
                float s = softplus100(acc[i][nt][r]);
                if (MODE == 1) {
                    s *= 0.70710678118654752f;
                    const int ch = chb + r;
                    if (ch >= 253)  // splice x * 1/sqrt2 (skip-concat)
                        s = xst[pt * 4 + (ch - 253)] * 0.70710678118654752f;
                }
                vv[r] = s;
            }
            __hip_bfloat162 p01 = __float22bfloat162_rn(float2{vv[0], vv[1]});
            __hip_bfloat162 p23 = __float22bfloat162_rn(float2{vv[2], vv[3]});
            uint2 pk;
            pk.x = *(unsigned int*)&p01;
            pk.y = *(unsigned int*)&p23;
            *(uint2*)(act + pt * LDA + chb) = pk;
        }
    }

    __syncthreads();   // writes visible before next layer reads
}

// Full network for one tile of NT*16 points starting at base_pt.
template <int NT>
__device__ __forceinline__ void run_net(
    const float* __restrict__ x, float* __restrict__ out,
    const unsigned short* __restrict__ wsW, const float* __restrict__ wsB,
    unsigned short* act, float* xst,
    int base_pt, int npts, int tid)
{
    const int wave = tid >> 6, lane = tid & 63;
    const int quad = lane >> 4, l15 = lane & 15;

    // stage x into act channels 0..2, zero-pad to 32 (K-pad for layer 0)
    for (int i = tid; i < NT * 16 * 32; i += 256) {
        const int pt = i >> 5, ch = i & 31;
        const int ptg = base_pt + pt;
        float v = 0.0f;
        if (ch < 3 && ptg < npts) v = x[ptg * 3 + ch];
        act[pt * LDA + ch] = bf16_rne(v);
        if (ch < 4) xst[pt * 4 + ch] = (ch < 3) ? v : 0.0f;
    }
    __syncthreads();

    layer_mm<1, 0, NT>(wsW + OFFW0, wsB + 0 * 256, act, xst, wave, lane);
    layer_mm<8, 0, NT>(wsW + OFFW1, wsB + 1 * 256, act, xst, wave, lane);
    layer_mm<8, 0, NT>(wsW + OFFW2, wsB + 2 * 256, act, xst, wave, lane);
    layer_mm<8, 1, NT>(wsW + OFFW3, wsB + 3 * 256, act, xst, wave, lane);
    layer_mm<8, 0, NT>(wsW + OFFW4, wsB + 4 * 256, act, xst, wave, lane);
    layer_mm<8, 0, NT>(wsW + OFFW5, wsB + 5 * 256, act, xst, wave, lane);
    layer_mm<8, 0, NT>(wsW + OFFW6, wsB + 6 * 256, act, xst, wave, lane);

    // layer 7: 256 -> 8. Wave w (w < NT) handles its own 16 points.
    // No barrier needed after: act is not touched again.
    if (wave < NT) {
        const float4 b4 = *(const float4*)(wsB + OFFB7 + quad * 4);  // quads>=2: zeros
        f32x4 acc = f32x4{b4.x, b4.y, b4.z, b4.w};
        const unsigned short* w7 = wsW + OFFW7;
#pragma unroll
        for (int kk = 0; kk < 8; ++kk) {
            bf16x8 bfr = *(const bf16x8*)(act + (wave * 16 + l15) * LDA + kk * 32 + quad * 8);
            bf16x8 afr = *(const bf16x8*)(w7 + (kk * 64 + lane) * 8);
            acc = __builtin_amdgcn_mfma_f32_16x16x32_bf16(afr, bfr, acc, 0, 0, 0);
        }
        // quad0 lanes have ch0-3, quad1 lanes ch4-7 (for pt = wave*16+l15).
        // Gather quad1's values into quad0 via shfl, then CSG + store.
        float u0 = __shfl(acc[0], l15 + 16);
        float u1 = __shfl(acc[1], l15 + 16);
        float u2 = __shfl(acc[2], l15 + 16);
        float u3 = __shfl(acc[3], l15 + 16);
        if (quad == 0) {
            const int ptg = base_pt + wave * 16 + l15;
            if (ptg < npts) {
                const float v0 = acc[0], v1 = acc[1], v2 = acc[2], v3 = acc[3];
                const float v4 = u0, v5 = u1, v6 = u2, v7 = u3;
                const float m23   = fminf(v2, v3);
                const float m67   = fmaxf(v6, v7);
                const float m4567 = fminf(fminf(v4, v5), m67);
                const float h     = fmaxf(fmaxf(v0, v1), fmaxf(m23, m4567));
                float* o = out + (long)ptg * 9;
                o[0] = h;
                o[1] = v0; o[2] = v1; o[3] = v2; o[4] = v3;
                o[5] = v4; o[6] = v5; o[7] = v6; o[8] = v7;
            }
        }
    }
}

__global__ __launch_bounds__(256, 5)
void nhrep_main(const float* __restrict__ x, float* __restrict__ out,
                const unsigned short* __restrict__ wsW,
                const float* __restrict__ wsB, int npts, int nbig)
{
    __shared__ unsigned short act[48 * LDA];   // 25344 B
    __shared__ float xst[48 * 4];              // 768 B   -> 26112 B total
    const int b = blockIdx.x;
    if (b < nbig) {
        run_net<3>(x, out, wsW, wsB, act, xst, b * 48, npts, threadIdx.x);
    } else {
        run_net<2>(x, out, wsW, wsB, act, xst, nbig * 48 + (b - nbig) * 32, npts, threadIdx.x);
    }
}

// ---------------------------------------------------------------------------
// Fused prepack: all 8 W's -> bf16 A-operand fragments + padded biases.
// Frag (mt,kk,lane,j) = W^T[mt*16+(lane&15)][kk*32+(lane>>4)*8+j], zero-padded.
// ---------------------------------------------------------------------------
struct PackArgs {
    const float* W[8];
    const float* b[8];
};

#define TOTAL_FRAGS 50688
#define TOTAL_BIAS  1808

__global__ void prepack_all(PackArgs args, unsigned short* __restrict__ dstW,
                            float* __restrict__ dstB)
{
    const int t = blockIdx.x * blockDim.x + threadIdx.x;
    const int FB[9]  = {0, 1024, 9216, 17408, 25600, 33792, 41984, 50176, 50688};
    const int KKs[8] = {1, 8, 8, 8, 8, 8, 8, 8};
    const int ind[8] = {3, 256, 256, 256, 256, 256, 256, 256};
    const int outd[8]= {256, 256, 256, 253, 256, 256, 256, 8};

    if (t < TOTAL_FRAGS) {
        int l = 0;
        while (t >= FB[l + 1]) ++l;
        const int f    = t - FB[l];
        const int lane = f & 63;
        const int kk   = (f >> 6) % KKs[l];
        const int mt   = f / (64 * KKs[l]);
        const int o    = mt * 16 + (lane & 15);
        const int kb   = kk * 32 + (lane >> 4) * 8;
        const float* W = args.W[l];
        const int in_d = ind[l], out_d = outd[l];

        unsigned short v[8];
#pragma unroll
        for (int j = 0; j < 8; ++j) {
            const int k = kb + j;
            float w = 0.0f;
            if (k < in_d && o < out_d) w = W[k * out_d + o];
            unsigned int u = __float_as_uint(w);
            v[j] = (unsigned short)((u + 0x7FFFu + ((u >> 16) & 1u)) >> 16);
        }
        uint4 p;
        p.x = (unsigned int)v[0] | ((unsigned int)v[1] << 16);
        p.y = (unsigned int)v[2] | ((unsigned int)v[3] << 16);
        p.z = (unsigned int)v[4] | ((unsigned int)v[5] << 16);
        p.w = (unsigned int)v[6] | ((unsigned int)v[7] << 16);
        *(uint4*)(dstW + (long)t * 8) = p;
    } else if (t < TOTAL_FRAGS + TOTAL_BIAS) {
        const int u = t - TOTAL_FRAGS;
        const int l = (u < 1792) ? (u >> 8) : 7;
        const int idx = (l < 7) ? (u & 255) : (u - 1792);
        dstB[u] = (idx < outd[l]) ? args.b[l][idx] : 0.0f;
    }
}

extern "C" void kernel_launch(void* const* d_in, const int* in_sizes, int n_in,
                              void* d_out, int out_size, void* d_ws, size_t ws_size,
                              hipStream_t stream)
{
    const float* x = (const float*)d_in[0];
    unsigned short* wsW = (unsigned short*)d_ws;
    float* wsB = (float*)((char*)d_ws + WSB_BYTE_OFF);

    PackArgs pa;
    for (int l = 0; l < 8; ++l) {
        pa.W[l] = (const float*)d_in[1 + 2 * l];
        pa.b[l] = (const float*)d_in[2 + 2 * l];
    }
    const int ptot = TOTAL_FRAGS + TOTAL_BIAS;
    prepack_all<<<(ptot + 255) / 256, 256, 0, stream>>>(pa, wsW, wsB);

    const int npts = in_sizes[0] / 3;   // 100000
    // Mixed grid: nbig 48-pt tiles (one full round at 5 blocks/CU), then
    // 32-pt tiles for the remainder (cheaper round 2, also full-width).
    int nbig = 1280;                     // 5 blocks/CU * 256 CUs
    long big_pts = (long)nbig * 48;
    int nsmall;
    if (big_pts >= npts) {
        nbig = (npts + 47) / 48;
        nsmall = 0;
    } else {
        nsmall = (int)((npts - big_pts + 31) / 32);
    }
    nhrep_main<<<nbig + nsmall, 256, 0, stream>>>(x, (float*)d_out, wsW, wsB, npts, nbig);
}

// Round 4
// 208.408 us; speedup vs baseline: 2.2073x; 1.0097x over previous
//
#include <hip/hip_runtime.h>
#include <hip/hip_bf16.h>

// ---------------------------------------------------------------------------
// NHRepNet fused forward, Round 4: 8-wave blocks for the 64-reg occupancy tier.
//
// Key insight from R3 counters: reg file allocates power-of-2 slots per wave
// (m69: waves halve at 64/128/256). R3's 96 regs/wave -> 128-slot -> 4 waves/
// SIMD, 50% occupancy. R4: 512-thr blocks, wave owns 32 channels, acc[2][2] =
// 16 AGPR, target total <= 64 regs -> 8 waves/SIMD, 32 waves/CU (100% cap).
// Tile = 32 pts, LDS 17.4KB, 4 blocks/CU. Grid = 3125 (exact).
//
// Scale folding (carry a2 = max(t2,0)+log2(1+2^-|t2|), t2 = 144.2695*z):
//   h = (ln2/100)*a2;  layer l+1: t2' = W*a2 + 144.2695*b  (weight scale = 1!)
//   W0 *= 144.2695; W4 rows<253 *= 1/sqrt2, rows>=253 *= 144.2695/sqrt2;
//   W7 *= ln2/100; b0..b6 *= 144.2695; b7 raw. Softplus: 5 VALU ops, no muls.
// ---------------------------------------------------------------------------

using bf16x8 = __attribute__((ext_vector_type(8))) __bf16;
using f32x4  = __attribute__((ext_vector_type(4))) float;

#define LDA 264   // padded activation row stride (bf16): 528B row => free 2-way

#define OFFW0 0
#define OFFW1 8192
#define OFFW2 73728
#define OFFW3 139264
#define OFFW4 204800
#define OFFW5 270336
#define OFFW6 335872
#define OFFW7 401408
#define WSB_BYTE_OFF 811008   // fp32 bias region
#define OFFB7 1792            // L0..L6 at l*256; L7 at 1792 (16 floats, padded)

#define SCALE_T2 144.26950408889634f      // 100*log2(e)
#define INV_SQRT2 0.70710678118654752f
#define LN2_100 0.0069314718055994531f    // ln2/100

__device__ __forceinline__ float fast_exp2(float x) {
#if __has_builtin(__builtin_amdgcn_exp2f)
    return __builtin_amdgcn_exp2f(x);
#else
    return exp2f(x);
#endif
}
__device__ __forceinline__ float fast_log2(float x) {
#if __has_builtin(__builtin_amdgcn_logf)
    return __builtin_amdgcn_logf(x);
#else
    return log2f(x);
#endif
}

// a2 = max(t2,0) + log2(1 + 2^-|t2|)   (5 VALU: exp2(-abs mod), add, log2, max, add)
__device__ __forceinline__ float softplus_t2(float t2) {
    float e = fast_exp2(-fabsf(t2));
    float l = fast_log2(1.0f + e);
    return fmaxf(t2, 0.0f) + l;
}

__device__ __forceinline__ unsigned short bf16_rne(float f) {
    unsigned int u = __float_as_uint(f);
    unsigned int r = u + 0x7FFFu + ((u >> 16) & 1u);
    return (unsigned short)(r >> 16);
}

// One 256-out layer, in-place on act[32][LDA]. Wave w (of 8) owns channels
// [w*32, w*32+32) (m-tiles mt = w*2+i). MODE 0: softplus. MODE 1: layer-3
// (softplus; splice raw x into ch 253..255 — scales folded into W4).
template <int KK, int MODE>
__device__ __forceinline__ void layer_mm(
    const unsigned short* __restrict__ wfrag,
    const float* __restrict__ bias,
    unsigned short* act, const float* xst,
    int wave, int lane)
{
    const int quad = lane >> 4;
    const int l15  = lane & 15;

    f32x4 acc[2][2];
#pragma unroll
    for (int i = 0; i < 2; ++i) {
        const int chb = (wave * 2 + i) * 16 + quad * 4;
        const float4 b4 = *(const float4*)(bias + chb);
#pragma unroll
        for (int nt = 0; nt < 2; ++nt)
            acc[i][nt] = f32x4{b4.x, b4.y, b4.z, b4.w};
    }

#pragma unroll
    for (int kk = 0; kk < KK; ++kk) {
        bf16x8 bfr[2];
#pragma unroll
        for (int nt = 0; nt < 2; ++nt)
            bfr[nt] = *(const bf16x8*)(act + (nt * 16 + l15) * LDA + kk * 32 + quad * 8);
#pragma unroll
        for (int i = 0; i < 2; ++i) {
            const int mt = wave * 2 + i;
            bf16x8 afr = *(const bf16x8*)(wfrag + ((mt * KK + kk) * 64 + lane) * 8);
#pragma unroll
            for (int nt = 0; nt < 2; ++nt)
                acc[i][nt] = __builtin_amdgcn_mfma_f32_16x16x32_bf16(afr, bfr[nt], acc[i][nt], 0, 0, 0);
        }
    }

    __syncthreads();   // all waves done READING act

#pragma unroll
    for (int i = 0; i < 2; ++i) {
        const int chb = (wave * 2 + i) * 16 + quad * 4;
#pragma unroll
        for (int nt = 0; nt < 2; ++nt) {
            const int pt = nt * 16 + l15;
            float vv[4];
#pragma unroll
            for (int r = 0; r < 4; ++r) {
                float s = softplus_t2(acc[i][nt][r]);
                if (MODE == 1) {
                    const int ch = chb + r;
                    if (ch >= 253)  // splice raw x (W4 row scales absorb 144.27/sqrt2)
                        s = xst[pt * 4 + (ch - 253)];
                }
                vv[r] = s;
            }
            __hip_bfloat162 p01 = __float22bfloat162_rn(float2{vv[0], vv[1]});
            __hip_bfloat162 p23 = __float22bfloat162_rn(float2{vv[2], vv[3]});
            uint2 pk;
            pk.x = *(unsigned int*)&p01;
            pk.y = *(unsigned int*)&p23;
            *(uint2*)(act + pt * LDA + chb) = pk;
        }
    }

    __syncthreads();   // writes visible before next layer reads
}

__global__ __launch_bounds__(512, 8)
void nhrep_main(const float* __restrict__ x, float* __restrict__ out,
                const unsigned short* __restrict__ wsW,
                const float* __restrict__ wsB, int npts)
{
    __shared__ unsigned short act[32 * LDA];   // 16896 B
    __shared__ float xst[32 * 4];              // 512 B  -> 17408 B total
    const int tid  = threadIdx.x;
    const int wave = tid >> 6, lane = tid & 63;
    const int quad = lane >> 4, l15 = lane & 15;
    const int base_pt = blockIdx.x * 32;

    // stage x into act channels 0..2, zero-pad to 32 (K-pad for layer 0)
    for (int i = tid; i < 32 * 32; i += 512) {
        const int pt = i >> 5, ch = i & 31;
        const int ptg = base_pt + pt;
        float v = 0.0f;
        if (ch < 3 && ptg < npts) v = x[ptg * 3 + ch];
        act[pt * LDA + ch] = bf16_rne(v);
        if (ch < 4) xst[pt * 4 + ch] = (ch < 3) ? v : 0.0f;
    }
    __syncthreads();

    layer_mm<1, 0>(wsW + OFFW0, wsB + 0 * 256, act, xst, wave, lane);
    layer_mm<8, 0>(wsW + OFFW1, wsB + 1 * 256, act, xst, wave, lane);
    layer_mm<8, 0>(wsW + OFFW2, wsB + 2 * 256, act, xst, wave, lane);
    layer_mm<8, 1>(wsW + OFFW3, wsB + 3 * 256, act, xst, wave, lane);
    layer_mm<8, 0>(wsW + OFFW4, wsB + 4 * 256, act, xst, wave, lane);
    layer_mm<8, 0>(wsW + OFFW5, wsB + 5 * 256, act, xst, wave, lane);
    layer_mm<8, 0>(wsW + OFFW6, wsB + 6 * 256, act, xst, wave, lane);

    // layer 7: 256 -> 8 (W7 pre-scaled by ln2/100, b7 raw). Waves 0,1 handle
    // 16 pts each; act is not written again, so no barrier needed.
    if (wave < 2) {
        const float4 b4 = *(const float4*)(wsB + OFFB7 + quad * 4);  // quads>=2: zeros
        f32x4 acc = f32x4{b4.x, b4.y, b4.z, b4.w};
        const unsigned short* w7 = wsW + OFFW7;
#pragma unroll
        for (int kk = 0; kk < 8; ++kk) {
            bf16x8 bfr = *(const bf16x8*)(act + (wave * 16 + l15) * LDA + kk * 32 + quad * 8);
            bf16x8 afr = *(const bf16x8*)(w7 + (kk * 64 + lane) * 8);
            acc = __builtin_amdgcn_mfma_f32_16x16x32_bf16(afr, bfr, acc, 0, 0, 0);
        }
        // quad0 lanes hold ch0-3, quad1 ch4-7 for pt = wave*16+l15
        float u0 = __shfl(acc[0], l15 + 16);
        float u1 = __shfl(acc[1], l15 + 16);
        float u2 = __shfl(acc[2], l15 + 16);
        float u3 = __shfl(acc[3], l15 + 16);
        if (quad == 0) {
            const int ptg = base_pt + wave * 16 + l15;
            if (ptg < npts) {
                const float v0 = acc[0], v1 = acc[1], v2 = acc[2], v3 = acc[3];
                const float v4 = u0, v5 = u1, v6 = u2, v7 = u3;
                const float m23   = fminf(v2, v3);
                const float m67   = fmaxf(v6, v7);
                const float m4567 = fminf(fminf(v4, v5), m67);
                const float h     = fmaxf(fmaxf(v0, v1), fmaxf(m23, m4567));
                float* o = out + (long)ptg * 9;
                o[0] = h;
                o[1] = v0; o[2] = v1; o[3] = v2; o[4] = v3;
                o[5] = v4; o[6] = v5; o[7] = v6; o[8] = v7;
            }
        }
    }
}

// ---------------------------------------------------------------------------
// Fused prepack with scale folding. Frag (mt,kk,lane,j) =
// scale(l,k) * W^T[mt*16+(lane&15)][k = kk*32+(lane>>4)*8+j], zero-padded.
// ---------------------------------------------------------------------------
struct PackArgs {
    const float* W[8];
    const float* b[8];
};

#define TOTAL_FRAGS 50688
#define TOTAL_BIAS  1808

__global__ void prepack_all(PackArgs args, unsigned short* __restrict__ dstW,
                            float* __restrict__ dstB)
{
    const int t = blockIdx.x * blockDim.x + threadIdx.x;
    const int FB[9]  = {0, 1024, 9216, 17408, 25600, 33792, 41984, 50176, 50688};
    const int KKs[8] = {1, 8, 8, 8, 8, 8, 8, 8};
    const int ind[8] = {3, 256, 256, 256, 256, 256, 256, 256};
    const int outd[8]= {256, 256, 256, 253, 256, 256, 256, 8};

    if (t < TOTAL_FRAGS) {
        int l = 0;
        while (t >= FB[l + 1]) ++l;
        const int f    = t - FB[l];
        const int lane = f & 63;
        const int kk   = (f >> 6) % KKs[l];
        const int mt   = f / (64 * KKs[l]);
        const int o    = mt * 16 + (lane & 15);
        const int kb   = kk * 32 + (lane >> 4) * 8;
        const float* W = args.W[l];
        const int in_d = ind[l], out_d = outd[l];

        unsigned short v[8];
#pragma unroll
        for (int j = 0; j < 8; ++j) {
            const int k = kb + j;
            float w = 0.0f;
            if (k < in_d && o < out_d) {
                float sc = 1.0f;
                if (l == 0) sc = SCALE_T2;
                else if (l == 4) sc = (k < 253) ? INV_SQRT2 : (SCALE_T2 * INV_SQRT2);
                else if (l == 7) sc = LN2_100;
                w = W[k * out_d + o] * sc;
            }
            unsigned int u = __float_as_uint(w);
            v[j] = (unsigned short)((u + 0x7FFFu + ((u >> 16) & 1u)) >> 16);
        }
        uint4 p;
        p.x = (unsigned int)v[0] | ((unsigned int)v[1] << 16);
        p.y = (unsigned int)v[2] | ((unsigned int)v[3] << 16);
        p.z = (unsigned int)v[4] | ((unsigned int)v[5] << 16);
        p.w = (unsigned int)v[6] | ((unsigned int)v[7] << 16);
        *(uint4*)(dstW + (long)t * 8) = p;
    } else if (t < TOTAL_FRAGS + TOTAL_BIAS) {
        const int u = t - TOTAL_FRAGS;
        const int l = (u < 1792) ? (u >> 8) : 7;
        const int idx = (l < 7) ? (u & 255) : (u - 1792);
        const float sc = (l < 7) ? SCALE_T2 : 1.0f;   // b7 stays in output units
        dstB[u] = (idx < outd[l]) ? args.b[l][idx] * sc : 0.0f;
    }
}

extern "C" void kernel_launch(void* const* d_in, const int* in_sizes, int n_in,
                              void* d_out, int out_size, void* d_ws, size_t ws_size,
                              hipStream_t stream)
{
    const float* x = (const float*)d_in[0];
    unsigned short* wsW = (unsigned short*)d_ws;
    float* wsB = (float*)((char*)d_ws + WSB_BYTE_OFF);

    PackArgs pa;
    for (int l = 0; l < 8; ++l) {
        pa.W[l] = (const float*)d_in[1 + 2 * l];
        pa.b[l] = (const float*)d_in[2 + 2 * l];
    }
    const int ptot = TOTAL_FRAGS + TOTAL_BIAS;
    prepack_all<<<(ptot + 255) / 256, 256, 0, stream>>>(pa, wsW, wsB);

    const int npts = in_sizes[0] / 3;            // 100000
    const int nblk = (npts + 31) / 32;           // 3125 exactly
    nhrep_main<<<nblk, 512, 0, stream>>>(x, (float*)d_out, wsW, wsB, npts);
}